// Round 8
// baseline (458.888 us; speedup 1.0000x reference)
//
#include <hip/hip_runtime.h>

#define EDIM 256
#define NROW 16384
#define NCODE 16384
#define NBN 128
#define MARGIN 2.0e-4f

typedef _Float16 f16x8 __attribute__((ext_vector_type(8)));
typedef _Float16 f16x4 __attribute__((ext_vector_type(4)));
typedef float f32x4 __attribute__((ext_vector_type(4)));

__device__ __forceinline__ void gll16(const void* g, void* l) {
  __builtin_amdgcn_global_load_lds((const __attribute__((address_space(1))) void*)g,
                                   (__attribute__((address_space(3))) void*)l, 16, 0, 0);
}
__device__ __forceinline__ void gll4(const void* g, void* l) {
  __builtin_amdgcn_global_load_lds((const __attribute__((address_space(1))) void*)g,
                                   (__attribute__((address_space(3))) void*)l, 4, 0, 0);
}

// ||e_j||^2 (validated reduce, bit-identical) + Eh = f16(e * 2^10) fused
__global__ __launch_bounds__(256) void k_prep_e(const float* __restrict__ e,
                                                float* __restrict__ es,
                                                _Float16* __restrict__ Eh) {
  const int row = blockIdx.x * 4 + (threadIdx.x >> 6);
  const int lane = threadIdx.x & 63;
  float4 v = *(const float4*)&e[row * EDIM + lane * 4];
  f16x4 h;
  h[0] = (_Float16)(v.x * 1024.0f);
  h[1] = (_Float16)(v.y * 1024.0f);
  h[2] = (_Float16)(v.z * 1024.0f);
  h[3] = (_Float16)(v.w * 1024.0f);
  *(f16x4*)&Eh[row * EDIM + lane * 4] = h;
  double s = (double)v.x * v.x + (double)v.y * v.y + (double)v.z * v.z + (double)v.w * v.w;
#pragma unroll
  for (int off = 32; off > 0; off >>= 1) s += __shfl_down(s, off, 64);
  if (lane == 0) es[row] = (float)s;
}

// fallback-only es kernel (identical math)
__global__ __launch_bounds__(256) void k_es(const float* __restrict__ e,
                                            float* __restrict__ es) {
  const int row = blockIdx.x * 4 + (threadIdx.x >> 6);
  const int lane = threadIdx.x & 63;
  float4 v = *(const float4*)&e[row * EDIM + lane * 4];
  double s = (double)v.x * v.x + (double)v.y * v.y + (double)v.z * v.z + (double)v.w * v.w;
#pragma unroll
  for (int off = 32; off > 0; off >>= 1) s += __shfl_down(s, off, 64);
  if (lane == 0) es[row] = (float)s;
}

// z -> Zh [m][k] f16. 512 blocks x 32 rows, +1-padded LDS (conflict-free).
__global__ __launch_bounds__(256) void k_cvt_z(const float* __restrict__ z,
                                               _Float16* __restrict__ Zh) {
  __shared__ float zl[EDIM * 33];  // [c][33] ~33.8KB
  const int t = threadIdx.x;
  const int rb = blockIdx.x;  // 512 blocks
  const int bb = rb >> 5;
  const int hw0 = (rb & 31) << 5;
  const float* zbase = z + (size_t)bb * EDIM * 1024 + hw0;
#pragma unroll 4
  for (int rep = 0; rep < 32; ++rep) {
    int c = rep * 8 + (t >> 5);
    zl[c * 33 + (t & 31)] = zbase[(size_t)c * 1024 + (t & 31)];
  }
  __syncthreads();
  const int mloc = t >> 3, part = t & 7;
#pragma unroll
  for (int i = 0; i < 4; ++i) {
    int c0 = part * 32 + i * 8;
    f16x8 v;
#pragma unroll
    for (int j = 0; j < 8; ++j) v[j] = (_Float16)zl[(c0 + j) * 33 + mloc];
    *(f16x8*)&Zh[(size_t)(rb * 32 + mloc) * EDIM + c0] = v;
  }
}

// Phase A: f16 MFMA GEMM h = -2*(z.e). 128x128 tile, 4 waves, 64x64 wave tile.
// A: LDS (BK=64 double-buffer, 32KB) via gll16 with both-sides granule swizzle
// gran ^= (row&7) (8 banks x 2 lanes = free). B: direct L2->reg f16x8 loads
// (bit-identical bytes; no LDS). 4 steps => 4 barriers total.
__global__ __launch_bounds__(256) void k_gemm(const _Float16* __restrict__ Zh,
                                              const _Float16* __restrict__ Eh,
                                              float* __restrict__ lmin,
                                              uint4* __restrict__ masks) {
  __shared__ __align__(16) char smem[32768];  // A[2][128][64]f16

  const int tid = threadIdx.x;
  const int lane = tid & 63;
  const int wv = tid >> 6;
  const int wm = wv & 1, wn = wv >> 1;
  const int fr = lane & 15;
  const int fq = lane >> 4;

  // r5/r7 XCD swizzle + 16x16 supertiles (validated)
  const int bid = (int)blockIdx.x;
  const int wgid = (bid & 7) * 2048 + (bid >> 3);
  const int st = wgid >> 8, wi = wgid & 255;
  const int bm = ((st & 7) << 4) | (wi & 15);
  const int bn = ((st >> 3) << 4) | (wi >> 4);

  const char* zh_b = (const char*)Zh;  // row stride 512B
  const char* eh_b = (const char*)Eh;
  const char* ebase = eh_b + (size_t)(bn * 128 + wn * 64 + fr) * 512 + fq * 16;

  // stage A chunk: 128 rows x 128B (BK=64), source granule pre-swizzled by row&7
  auto stage = [&](int buf, int s) {
#pragma unroll
    for (int i = 0; i < 4; ++i) {
      const int L = (i * 256 + tid) * 16;  // byte in 16KB tile
      const int row = L >> 7, p = (L >> 4) & 7;
      gll16(zh_b + (size_t)(bm * 128 + row) * 512 + s * 128 + ((p ^ (row & 7)) * 16),
            smem + buf * 16384 + L);
    }
  };

  f32x4 acc[4][4];
#pragma unroll
  for (int i = 0; i < 4; ++i)
#pragma unroll
    for (int j = 0; j < 4; ++j) acc[i][j] = (f32x4)0.0f;

  stage(0, 0);
  __syncthreads();
  int buf = 0;
#pragma unroll 1
  for (int s = 0; s < 4; ++s) {
    if (s + 1 < 4) stage(buf ^ 1, s + 1);
    const char* aB = smem + buf * 16384;
    // ---- half 0 (k-granules s*8 + fq)
    {
      f16x8 bf[4], af[4];
#pragma unroll
      for (int ni = 0; ni < 4; ++ni)
        bf[ni] = *(const f16x8*)(ebase + (size_t)(ni * 16) * 512 + s * 128);
#pragma unroll
      for (int mi = 0; mi < 4; ++mi)
        af[mi] = *(const f16x8*)(aB + (wm * 64 + mi * 16 + fr) * 128 + ((fq ^ (fr & 7)) * 16));
#pragma unroll
      for (int mi = 0; mi < 4; ++mi)
#pragma unroll
        for (int ni = 0; ni < 4; ++ni)
          acc[mi][ni] = __builtin_amdgcn_mfma_f32_16x16x32_f16(af[mi], bf[ni], acc[mi][ni], 0, 0, 0);
    }
    // ---- half 1 (k-granules s*8 + 4 + fq)
    {
      f16x8 bf[4], af[4];
#pragma unroll
      for (int ni = 0; ni < 4; ++ni)
        bf[ni] = *(const f16x8*)(ebase + (size_t)(ni * 16) * 512 + s * 128 + 64);
#pragma unroll
      for (int mi = 0; mi < 4; ++mi)
        af[mi] = *(const f16x8*)(aB + (wm * 64 + mi * 16 + fr) * 128 + (((4 + fq) ^ (fr & 7)) * 16));
#pragma unroll
      for (int mi = 0; mi < 4; ++mi)
#pragma unroll
        for (int ni = 0; ni < 4; ++ni)
          acc[mi][ni] = __builtin_amdgcn_mfma_f32_16x16x32_f16(af[mi], bf[ni], acc[mi][ni], 0, 0, 0);
    }
    __syncthreads();
    buf ^= 1;
  }

  // ---- epilogue (validated r6/r7 ballot form). C/D: row=(lane>>4)*4+reg, col=lane&15
  float* rowsmin = (float*)smem;               // [128][2]
  float* rowminC = (float*)(smem + 1024);      // [128]
  unsigned short* msk16 = (unsigned short*)(smem + 1536);  // [128][8]
  const float sc = -0.001953125f;  // -2^-9
#pragma unroll
  for (int mi = 0; mi < 4; ++mi)
#pragma unroll
    for (int r = 0; r < 4; ++r) {
      float v = acc[mi][0][r] * sc;
      v = fminf(v, acc[mi][1][r] * sc);
      v = fminf(v, acc[mi][2][r] * sc);
      v = fminf(v, acc[mi][3][r] * sc);
#pragma unroll
      for (int off = 1; off < 16; off <<= 1) v = fminf(v, __shfl_xor(v, off, 64));
      if (fr == 0) rowsmin[(wm * 64 + mi * 16 + fq * 4 + r) * 2 + wn] = v;
    }
  __syncthreads();
  if (tid < 128) {
    float rm = fminf(rowsmin[tid * 2], rowsmin[tid * 2 + 1]);
    rowminC[tid] = rm;
    lmin[(size_t)bn * NROW + bm * 128 + tid] = rm;
  }
  __syncthreads();
#pragma unroll
  for (int mi = 0; mi < 4; ++mi)
#pragma unroll
    for (int r = 0; r < 4; ++r) {
      const int row = wm * 64 + mi * 16 + fq * 4 + r;
      const float thr = rowminC[row] + MARGIN;
#pragma unroll
      for (int ni = 0; ni < 4; ++ni) {
        unsigned long long bal = __ballot(acc[mi][ni][r] * sc <= thr);
        if (fr == 0) msk16[row * 8 + wn * 4 + ni] = (unsigned short)((bal >> (fq * 16)) & 0xffffull);
      }
    }
  __syncthreads();
  if (tid < 128)
    masks[(size_t)bn * NROW + bm * 128 + tid] = *(const uint4*)&msk16[tid * 8];
}

// Phase B: exact rescore. 512 blocks x 32 rows, 8 lanes/row (q8=t&7, quarter=q8&3).
// zs grouping (4 x 64-k double-fma, (s0+s1)+(s2+s3)) preserved bit-exactly;
// lexicographic (d,idx) combine over 3 shuffle levels keeps lowest-index rule.
__global__ __launch_bounds__(256) void k_rescore(const float* __restrict__ z,
                                                 const float* __restrict__ e,
                                                 const float* __restrict__ es,
                                                 const float* __restrict__ lmin,
                                                 const uint4* __restrict__ masks,
                                                 int* __restrict__ out) {
  extern __shared__ float zl[];             // [256][33]
  float* lmin_s = zl + EDIM * 33;           // [128][33]
  const int t = threadIdx.x;
  const int rb = (int)blockIdx.x;           // 512 blocks
  const int bb = rb >> 5;
  const int hw0 = (rb & 31) << 5;
  const int r0 = rb * 32;
  const float* zbase = z + (size_t)bb * EDIM * 1024 + hw0;
#pragma unroll 4
  for (int rep = 0; rep < 32; ++rep) {
    int c = rep * 8 + (t >> 5);
    zl[c * 33 + (t & 31)] = zbase[(size_t)c * 1024 + (t & 31)];
  }
#pragma unroll 4
  for (int rep = 0; rep < 16; ++rep) {
    int bn = rep * 8 + (t >> 5);
    lmin_s[bn * 33 + (t & 31)] = lmin[(size_t)bn * NROW + r0 + (t & 31)];
  }
  __syncthreads();

  const int r = t >> 3, q8 = t & 7, q = q8 & 3;
  const int row = r0 + r;

  // zs quarter q (validated 64-k double-fma chain); lanes q8 and q8+4 duplicate
  double sq = 0.0;
  {
    const float* zq = zl + (q * 64) * 33 + r;
    for (int k = 0; k < 64; ++k) {
      float v = zq[k * 33];
      sq = fma((double)v, (double)v, sq);
    }
  }
  double s01 = sq + __shfl_xor(sq, 1, 64);    // (sq0+sq1) / (sq2+sq3)
  double zsd = s01 + __shfl_xor(s01, 2, 64);  // exact validated grouping
  const float zs = (float)zsd;

  float g = 3.402823466e+38f;
#pragma unroll
  for (int j = 0; j < 16; ++j) g = fminf(g, lmin_s[(q8 * 16 + j) * 33 + r]);
  g = fminf(g, __shfl_xor(g, 1, 64));
  g = fminf(g, __shfl_xor(g, 2, 64));
  g = fminf(g, __shfl_xor(g, 4, 64));
  const float thr = g + MARGIN;

  float bestd = 3.402823466e+38f;
  int besti = 0x7fffffff;
#pragma unroll 1
  for (int j = 0; j < 16; ++j) {
    const int bn = q8 * 16 + j;  // ascending within lane
    if (lmin_s[bn * 33 + r] <= thr) {
      uint4 mk = masks[(size_t)bn * NROW + row];
      unsigned w[4] = {mk.x, mk.y, mk.z, mk.w};
#pragma unroll 1
      for (int qq = 0; qq < 4; ++qq) {
        unsigned u = w[qq];
        while (u) {
          int b = __ffs(u) - 1;
          u &= u - 1;
          const int code = bn * 128 + qq * 32 + b;
          const float* ep = e + (size_t)code * EDIM;
          float dot = 0.0f;
          for (int k = 0; k < EDIM; k += 4) {  // ascending k, sequential fp32 chain
            float4 ev = *(const float4*)(ep + k);
            dot = fmaf(zl[(k + 0) * 33 + r], ev.x, dot);
            dot = fmaf(zl[(k + 1) * 33 + r], ev.y, dot);
            dot = fmaf(zl[(k + 2) * 33 + r], ev.z, dot);
            dot = fmaf(zl[(k + 3) * 33 + r], ev.w, dot);
          }
          float d = (zs + es[code]) - 2.0f * dot;
          if (d < bestd) {
            bestd = d;
            besti = code;
          }
        }
      }
    }
  }
#pragma unroll
  for (int off = 1; off <= 4; off <<= 1) {
    float ov = __shfl_xor(bestd, off, 64);
    int oi = __shfl_xor(besti, off, 64);
    if (ov < bestd || (ov == bestd && oi < besti)) {
      bestd = ov;
      besti = oi;
    }
  }
  if (q8 == 0) out[row] = besti;
}

// ================= fallback (round-1 verbatim, passed at 1654us) =================
__global__ __launch_bounds__(256) void k_merge(const float* __restrict__ candv,
                                               const int* __restrict__ candi,
                                               int* __restrict__ out) {
  int n = blockIdx.x * 256 + threadIdx.x;
  float v0 = candv[n], v1 = candv[NROW + n];
  int i0 = candi[n], i1 = candi[NROW + n];
  out[n] = (v1 < v0) ? i1 : i0;
}

template <int SPLIT>
__global__ __launch_bounds__(256, 2) void k_main_fb(const float* __restrict__ z,
                                                    const float* __restrict__ e,
                                                    const float* __restrict__ es,
                                                    float* __restrict__ candv,
                                                    int* __restrict__ candi,
                                                    int* __restrict__ outd) {
  extern __shared__ char smemc[];
  float* As = (float*)smemc;
  float* Bs = (float*)(smemc + 16384);
  double* zred = (double*)(smemc + 16384 + 32768);
  float* zsf = (float*)(smemc + 16384 + 32768 + 2048);
  const int tid = threadIdx.x;
  const int lane = tid & 63;
  const int wv = tid >> 6;
  const int tm = tid & 7;
  const int tn = tid >> 3;
  const int rt = (int)blockIdx.x / SPLIT;
  const int sp = (int)blockIdx.x % SPLIT;
  const int bb = rt >> 4;
  const int hw0 = (rt & 15) << 6;
  const float* zb = z + bb * (EDIM * 1024) + hw0;
  const int codeBase = sp * (NCODE / SPLIT);
  const int NSTEP = (NCODE / SPLIT) / 256 * 8;
  auto stageA = [&](int buf, int gts) {
    const int k0 = (gts & 7) * 32;
    const float* g0 = zb + (size_t)k0 * 1024 + lane;
    float* l0 = As + buf * 2048 + (wv * 8) * 64;
#pragma unroll
    for (int s = 0; s < 8; ++s) gll4(g0 + (size_t)(wv * 8 + s) * 1024, l0 + s * 64);
  };
  float4 bpre[8];
  auto loadB = [&](int gts) {
    const int ct = gts >> 3, k0 = (gts & 7) * 32;
    const float* g = e + (size_t)(codeBase + ct * 256 + tid) * 256 + k0;
#pragma unroll
    for (int s = 0; s < 8; ++s) bpre[s] = *(const float4*)(g + s * 4);
  };
  auto writeB = [&](int buf) {
    float* bw_ = Bs + buf * 8192 + tid;
#pragma unroll
    for (int s = 0; s < 8; ++s) {
      bw_[(4 * s + 0) * 256] = bpre[s].x;
      bw_[(4 * s + 1) * 256] = bpre[s].y;
      bw_[(4 * s + 2) * 256] = bpre[s].z;
      bw_[(4 * s + 3) * 256] = bpre[s].w;
    }
  };
  stageA(0, 0);
  loadB(0);
  {
    const int m = tid & 63, qt = tid >> 6;
    const float* zp = zb + (size_t)(qt * 64) * 1024 + m;
    double s = 0.0;
    for (int k = 0; k < 64; ++k) {
      float v = zp[(size_t)k * 1024];
      s = fma((double)v, (double)v, s);
    }
    zred[qt * 64 + m] = s;
  }
  writeB(0);
  __syncthreads();
  if (tid < 64) {
    double sz = (zred[tid] + zred[64 + tid]) + (zred[128 + tid] + zred[192 + tid]);
    zsf[tid] = (float)sz;
  }
  __syncthreads();
  float zsr[8];
#pragma unroll
  for (int i = 0; i < 8; ++i) zsr[i] = zsf[tm * 8 + i];
  __syncthreads();
  float bestv[8];
  int besti[8];
#pragma unroll
  for (int i = 0; i < 8; ++i) {
    bestv[i] = 3.402823466e+38f;
    besti[i] = 0;
  }
  float acc[8][8];
  int cur = 0;
#pragma unroll 1
  for (int step = 0; step < NSTEP; ++step) {
    const int kc = step & 7, ct = step >> 3;
    if (step + 1 < NSTEP) {
      stageA(cur ^ 1, step + 1);
      loadB(step + 1);
    }
    if (kc == 0) {
#pragma unroll
      for (int i = 0; i < 8; ++i)
#pragma unroll
        for (int j = 0; j < 8; ++j) acc[i][j] = 0.0f;
    }
    const float* ak = As + cur * 2048 + tm * 8;
    const float* bk = Bs + cur * 8192 + tn * 8;
#pragma unroll 4
    for (int k = 0; k < 32; ++k) {
      float4 a0 = *(const float4*)(ak + k * 64);
      float4 a1 = *(const float4*)(ak + k * 64 + 4);
      float4 b0 = *(const float4*)(bk + k * 256);
      float4 b1 = *(const float4*)(bk + k * 256 + 4);
      float av[8] = {a0.x, a0.y, a0.z, a0.w, a1.x, a1.y, a1.z, a1.w};
      float bw[8] = {b0.x, b0.y, b0.z, b0.w, b1.x, b1.y, b1.z, b1.w};
#pragma unroll
      for (int i = 0; i < 8; ++i)
#pragma unroll
        for (int j = 0; j < 8; ++j) acc[i][j] = fmaf(av[i], bw[j], acc[i][j]);
    }
    if (step + 1 < NSTEP) writeB(cur ^ 1);
    if (kc == 7) {
      const int cb = codeBase + ct * 256 + tn * 8;
#pragma unroll
      for (int j = 0; j < 8; ++j) {
        float ej = es[cb + j];
#pragma unroll
        for (int i = 0; i < 8; ++i) {
          float d = (zsr[i] + ej) - 2.0f * acc[i][j];
          if (d < bestv[i]) {
            bestv[i] = d;
            besti[i] = cb + j;
          }
        }
      }
    }
    __syncthreads();
    cur ^= 1;
  }
  float* Lv = (float*)(smemc + 16384);
  int* Li = (int*)(smemc + 16384 + 8192);
#pragma unroll
  for (int i = 0; i < 8; ++i) {
    Lv[(tm * 8 + i) * 32 + tn] = bestv[i];
    Li[(tm * 8 + i) * 32 + tn] = besti[i];
  }
  __syncthreads();
  if (tid < 64) {
    float bv = Lv[tid * 32];
    int bi = Li[tid * 32];
#pragma unroll 1
    for (int g2 = 1; g2 < 32; ++g2) {
      float v = Lv[tid * 32 + g2];
      int ii = Li[tid * 32 + g2];
      if (v < bv || (v == bv && ii < bi)) {
        bv = v;
        bi = ii;
      }
    }
    if (SPLIT == 1) outd[rt * 64 + tid] = bi;
    else {
      candv[sp * NROW + rt * 64 + tid] = bv;
      candi[sp * NROW + rt * 64 + tid] = bi;
    }
  }
}

extern "C" void kernel_launch(void* const* d_in, const int* in_sizes, int n_in,
                              void* d_out, int out_size, void* d_ws, size_t ws_size,
                              hipStream_t stream) {
  const float* z = (const float*)d_in[0];
  const float* e = (const float*)d_in[1];
  int* out = (int*)d_out;

  char* ws = (char*)d_ws;
  float* es = (float*)ws;
  const size_t off_zh = 65536;
  const size_t off_eh = off_zh + (size_t)NROW * EDIM * 2;
  const size_t off_lmin = off_eh + (size_t)NCODE * EDIM * 2;
  const size_t off_masks = off_lmin + (size_t)NROW * NBN * 4;
  const size_t need = off_masks + (size_t)NROW * NBN * 16;

  if (ws_size >= need) {
    _Float16* Zh = (_Float16*)(ws + off_zh);
    _Float16* Eh = (_Float16*)(ws + off_eh);
    float* lmin = (float*)(ws + off_lmin);
    uint4* masks = (uint4*)(ws + off_masks);
    k_prep_e<<<dim3(NCODE / 4), dim3(256), 0, stream>>>(e, es, Eh);
    k_cvt_z<<<dim3(512), dim3(256), 0, stream>>>(z, Zh);
    k_gemm<<<dim3(16384), dim3(256), 0, stream>>>(Zh, Eh, lmin, masks);
    const int rs_smem = (EDIM * 33 + NBN * 33) * 4;  // 50688
    hipFuncSetAttribute(reinterpret_cast<const void*>(&k_rescore),
                        hipFuncAttributeMaxDynamicSharedMemorySize, rs_smem);
    k_rescore<<<dim3(512), dim3(256), rs_smem, stream>>>(z, e, es, lmin, masks, out);
  } else {
    k_es<<<dim3(NCODE / 4), dim3(256), 0, stream>>>(e, es);
    float* candv = (float*)(ws + 65536);
    int* candi = (int*)(ws + 65536 + 131072);
    const size_t smem = 16384 + 65536;
    if (ws_size >= 65536 + 131072 + 131072) {
      hipFuncSetAttribute(reinterpret_cast<const void*>(&k_main_fb<2>),
                          hipFuncAttributeMaxDynamicSharedMemorySize, (int)smem);
      k_main_fb<2><<<dim3(512), dim3(256), smem, stream>>>(z, e, es, candv, candi, out);
      k_merge<<<dim3(NROW / 256), dim3(256), 0, stream>>>(candv, candi, out);
    } else {
      hipFuncSetAttribute(reinterpret_cast<const void*>(&k_main_fb<1>),
                          hipFuncAttributeMaxDynamicSharedMemorySize, (int)smem);
      k_main_fb<1><<<dim3(256), dim3(256), smem, stream>>>(z, e, es, candv, candi, out);
    }
  }
}

// Round 9
// 348.029 us; speedup vs baseline: 1.3185x; 1.3185x over previous
//
#include <hip/hip_runtime.h>

#define EDIM 256
#define NROW 16384
#define NCODE 16384
#define NBN 128
#define MARGIN 2.0e-4f

typedef _Float16 f16x8 __attribute__((ext_vector_type(8)));
typedef _Float16 f16x4 __attribute__((ext_vector_type(4)));
typedef float f32x4 __attribute__((ext_vector_type(4)));

__device__ __forceinline__ void gll16(const void* g, void* l) {
  __builtin_amdgcn_global_load_lds((const __attribute__((address_space(1))) void*)g,
                                   (__attribute__((address_space(3))) void*)l, 16, 0, 0);
}
__device__ __forceinline__ void gll4(const void* g, void* l) {
  __builtin_amdgcn_global_load_lds((const __attribute__((address_space(1))) void*)g,
                                   (__attribute__((address_space(3))) void*)l, 4, 0, 0);
}

// ||e_j||^2 (validated reduce, bit-identical) + Eh = f16(e * 2^10) fused
__global__ __launch_bounds__(256) void k_prep_e(const float* __restrict__ e,
                                                float* __restrict__ es,
                                                _Float16* __restrict__ Eh) {
  const int row = blockIdx.x * 4 + (threadIdx.x >> 6);
  const int lane = threadIdx.x & 63;
  float4 v = *(const float4*)&e[row * EDIM + lane * 4];
  f16x4 h;
  h[0] = (_Float16)(v.x * 1024.0f);
  h[1] = (_Float16)(v.y * 1024.0f);
  h[2] = (_Float16)(v.z * 1024.0f);
  h[3] = (_Float16)(v.w * 1024.0f);
  *(f16x4*)&Eh[row * EDIM + lane * 4] = h;
  double s = (double)v.x * v.x + (double)v.y * v.y + (double)v.z * v.z + (double)v.w * v.w;
#pragma unroll
  for (int off = 32; off > 0; off >>= 1) s += __shfl_down(s, off, 64);
  if (lane == 0) es[row] = (float)s;
}

// fallback-only es kernel (identical math)
__global__ __launch_bounds__(256) void k_es(const float* __restrict__ e,
                                            float* __restrict__ es) {
  const int row = blockIdx.x * 4 + (threadIdx.x >> 6);
  const int lane = threadIdx.x & 63;
  float4 v = *(const float4*)&e[row * EDIM + lane * 4];
  double s = (double)v.x * v.x + (double)v.y * v.y + (double)v.z * v.z + (double)v.w * v.w;
#pragma unroll
  for (int off = 32; off > 0; off >>= 1) s += __shfl_down(s, off, 64);
  if (lane == 0) es[row] = (float)s;
}

// z -> Zh [m][k] f16. 512 blocks x 32 rows, +1-padded LDS (validated r8).
__global__ __launch_bounds__(256) void k_cvt_z(const float* __restrict__ z,
                                               _Float16* __restrict__ Zh) {
  __shared__ float zl[EDIM * 33];
  const int t = threadIdx.x;
  const int rb = blockIdx.x;  // 512 blocks
  const int bb = rb >> 5;
  const int hw0 = (rb & 31) << 5;
  const float* zbase = z + (size_t)bb * EDIM * 1024 + hw0;
#pragma unroll 4
  for (int rep = 0; rep < 32; ++rep) {
    int c = rep * 8 + (t >> 5);
    zl[c * 33 + (t & 31)] = zbase[(size_t)c * 1024 + (t & 31)];
  }
  __syncthreads();
  const int mloc = t >> 3, part = t & 7;
#pragma unroll
  for (int i = 0; i < 4; ++i) {
    int c0 = part * 32 + i * 8;
    f16x8 v;
#pragma unroll
    for (int j = 0; j < 8; ++j) v[j] = (_Float16)zl[(c0 + j) * 33 + mloc];
    *(f16x8*)&Zh[(size_t)(rb * 32 + mloc) * EDIM + c0] = v;
  }
}

// Phase A: f16 MFMA GEMM h = -2*(z.e). r7 validated body (128x128 tile, 4 waves,
// 64x64 wave tile, BK=32, both operands LDS, conflict-free granule swizzle,
// ballot epilogue) + counted-vmcnt two-barrier pipeline (m201 pattern):
// stage G_{s+1}; s_waitcnt vmcnt(4) (G_s retired, G_{s+1} in flight); barrier;
// ds_read+MFMA (setprio); lgkmcnt(0); barrier. Never vmcnt(0) mid-loop.
__global__ __launch_bounds__(256, 2) void k_gemm(const _Float16* __restrict__ Zh,
                                                 const _Float16* __restrict__ Eh,
                                                 float* __restrict__ lmin,
                                                 uint4* __restrict__ masks) {
  __shared__ __align__(16) char smem[32768];  // A[2][128][32]f16 16KB | B[2][128][32]f16 16KB
  char* smemA = smem;
  char* smemB = smem + 16384;

  const int tid = threadIdx.x;
  const int lane = tid & 63;
  const int wv = tid >> 6;
  const int wm = wv & 1, wn = wv >> 1;
  const int fr = lane & 15;
  const int fq = lane >> 4;
  const int swz = (fq ^ ((fr >> 1) & 3)) * 16;  // read-side granule swizzle (validated)

  const int bid = (int)blockIdx.x;
  const int wgid = (bid & 7) * 2048 + (bid >> 3);
  const int st = wgid >> 8, wi = wgid & 255;
  const int bm = ((st & 7) << 4) | (wi & 15);
  const int bn = ((st >> 3) << 4) | (wi >> 4);

  const char* zh_b = (const char*)Zh;  // row stride 512B
  const char* eh_b = (const char*)Eh;

  auto stage = [&](int buf, int s) {  // 4 gll16/thread (2 A + 2 B)
#pragma unroll
    for (int i = 0; i < 2; ++i) {
      const int L = (i * 256 + tid) * 16;
      const int row = L >> 6, p = (L >> 4) & 3;
      const int gsw = (p ^ ((row >> 1) & 3)) * 16;  // source-side pre-swizzle (validated)
      gll16(zh_b + (size_t)(bm * 128 + row) * 512 + s * 64 + gsw, smemA + buf * 8192 + L);
      gll16(eh_b + (size_t)(bn * 128 + row) * 512 + s * 64 + gsw, smemB + buf * 8192 + L);
    }
  };

  f32x4 acc[4][4];
#pragma unroll
  for (int i = 0; i < 4; ++i)
#pragma unroll
    for (int j = 0; j < 4; ++j) acc[i][j] = (f32x4)0.0f;

  stage(0, 0);  // G_0
  int buf = 0;
#pragma unroll 1
  for (int s = 0; s < 8; ++s) {
    if (s + 1 < 8) stage(buf ^ 1, s + 1);  // G_{s+1} -> buf^1 (safe: all waves past
                                           // end-of-(s-1) barrier after reading buf^1)
    if (s + 1 < 8) {
      // wait only G_s (oldest 4); G_{s+1}'s 4 stay in flight across the barrier
      asm volatile("s_waitcnt vmcnt(4)\n\ts_barrier" ::: "memory");
    } else {
      asm volatile("s_waitcnt vmcnt(0)\n\ts_barrier" ::: "memory");
    }
    const char* aB = smemA + buf * 8192;
    const char* bB = smemB + buf * 8192;
    f16x8 af[4], bf[4];
#pragma unroll
    for (int mi = 0; mi < 4; ++mi)
      af[mi] = *(const f16x8*)(aB + (wm * 64 + mi * 16 + fr) * 64 + swz);
#pragma unroll
    for (int ni = 0; ni < 4; ++ni)
      bf[ni] = *(const f16x8*)(bB + (wn * 64 + ni * 16 + fr) * 64 + swz);
    __builtin_amdgcn_s_setprio(1);
#pragma unroll
    for (int mi = 0; mi < 4; ++mi)
#pragma unroll
      for (int ni = 0; ni < 4; ++ni)
        acc[mi][ni] = __builtin_amdgcn_mfma_f32_16x16x32_f16(af[mi], bf[ni], acc[mi][ni], 0, 0, 0);
    __builtin_amdgcn_s_setprio(0);
    // all my reads of buf retired before signaling; barrier releases buf for G_{s+2}
    asm volatile("s_waitcnt lgkmcnt(0)\n\ts_barrier" ::: "memory");
    buf ^= 1;
  }

  // ---- epilogue (validated r6/r7 ballot form). C/D: row=(lane>>4)*4+reg, col=lane&15
  float* rowsmin = (float*)smem;               // [128][2]
  float* rowminC = (float*)(smem + 1024);      // [128]
  unsigned short* msk16 = (unsigned short*)(smem + 1536);  // [128][8]
  const float sc = -0.001953125f;  // -2^-9
#pragma unroll
  for (int mi = 0; mi < 4; ++mi)
#pragma unroll
    for (int r = 0; r < 4; ++r) {
      float v = acc[mi][0][r] * sc;
      v = fminf(v, acc[mi][1][r] * sc);
      v = fminf(v, acc[mi][2][r] * sc);
      v = fminf(v, acc[mi][3][r] * sc);
#pragma unroll
      for (int off = 1; off < 16; off <<= 1) v = fminf(v, __shfl_xor(v, off, 64));
      if (fr == 0) rowsmin[(wm * 64 + mi * 16 + fq * 4 + r) * 2 + wn] = v;
    }
  __syncthreads();
  if (tid < 128) {
    float rm = fminf(rowsmin[tid * 2], rowsmin[tid * 2 + 1]);
    rowminC[tid] = rm;
    lmin[(size_t)bn * NROW + bm * 128 + tid] = rm;
  }
  __syncthreads();
#pragma unroll
  for (int mi = 0; mi < 4; ++mi)
#pragma unroll
    for (int r = 0; r < 4; ++r) {
      const int row = wm * 64 + mi * 16 + fq * 4 + r;
      const float thr = rowminC[row] + MARGIN;
#pragma unroll
      for (int ni = 0; ni < 4; ++ni) {
        unsigned long long bal = __ballot(acc[mi][ni][r] * sc <= thr);
        if (fr == 0) msk16[row * 8 + wn * 4 + ni] = (unsigned short)((bal >> (fq * 16)) & 0xffffull);
      }
    }
  __syncthreads();
  if (tid < 128)
    masks[(size_t)bn * NROW + bm * 128 + tid] = *(const uint4*)&msk16[tid * 8];
}

// Phase B: exact rescore (validated r8: 512 blocks x 32 rows, 8 lanes/row)
__global__ __launch_bounds__(256) void k_rescore(const float* __restrict__ z,
                                                 const float* __restrict__ e,
                                                 const float* __restrict__ es,
                                                 const float* __restrict__ lmin,
                                                 const uint4* __restrict__ masks,
                                                 int* __restrict__ out) {
  extern __shared__ float zl[];             // [256][33]
  float* lmin_s = zl + EDIM * 33;           // [128][33]
  const int t = threadIdx.x;
  const int rb = (int)blockIdx.x;           // 512 blocks
  const int bb = rb >> 5;
  const int hw0 = (rb & 31) << 5;
  const int r0 = rb * 32;
  const float* zbase = z + (size_t)bb * EDIM * 1024 + hw0;
#pragma unroll 4
  for (int rep = 0; rep < 32; ++rep) {
    int c = rep * 8 + (t >> 5);
    zl[c * 33 + (t & 31)] = zbase[(size_t)c * 1024 + (t & 31)];
  }
#pragma unroll 4
  for (int rep = 0; rep < 16; ++rep) {
    int bn = rep * 8 + (t >> 5);
    lmin_s[bn * 33 + (t & 31)] = lmin[(size_t)bn * NROW + r0 + (t & 31)];
  }
  __syncthreads();

  const int r = t >> 3, q8 = t & 7, q = q8 & 3;
  const int row = r0 + r;

  double sq = 0.0;
  {
    const float* zq = zl + (q * 64) * 33 + r;
    for (int k = 0; k < 64; ++k) {
      float v = zq[k * 33];
      sq = fma((double)v, (double)v, sq);
    }
  }
  double s01 = sq + __shfl_xor(sq, 1, 64);
  double zsd = s01 + __shfl_xor(s01, 2, 64);
  const float zs = (float)zsd;

  float g = 3.402823466e+38f;
#pragma unroll
  for (int j = 0; j < 16; ++j) g = fminf(g, lmin_s[(q8 * 16 + j) * 33 + r]);
  g = fminf(g, __shfl_xor(g, 1, 64));
  g = fminf(g, __shfl_xor(g, 2, 64));
  g = fminf(g, __shfl_xor(g, 4, 64));
  const float thr = g + MARGIN;

  float bestd = 3.402823466e+38f;
  int besti = 0x7fffffff;
#pragma unroll 1
  for (int j = 0; j < 16; ++j) {
    const int bn = q8 * 16 + j;
    if (lmin_s[bn * 33 + r] <= thr) {
      uint4 mk = masks[(size_t)bn * NROW + row];
      unsigned w[4] = {mk.x, mk.y, mk.z, mk.w};
#pragma unroll 1
      for (int qq = 0; qq < 4; ++qq) {
        unsigned u = w[qq];
        while (u) {
          int b = __ffs(u) - 1;
          u &= u - 1;
          const int code = bn * 128 + qq * 32 + b;
          const float* ep = e + (size_t)code * EDIM;
          float dot = 0.0f;
          for (int k = 0; k < EDIM; k += 4) {
            float4 ev = *(const float4*)(ep + k);
            dot = fmaf(zl[(k + 0) * 33 + r], ev.x, dot);
            dot = fmaf(zl[(k + 1) * 33 + r], ev.y, dot);
            dot = fmaf(zl[(k + 2) * 33 + r], ev.z, dot);
            dot = fmaf(zl[(k + 3) * 33 + r], ev.w, dot);
          }
          float d = (zs + es[code]) - 2.0f * dot;
          if (d < bestd) {
            bestd = d;
            besti = code;
          }
        }
      }
    }
  }
#pragma unroll
  for (int off = 1; off <= 4; off <<= 1) {
    float ov = __shfl_xor(bestd, off, 64);
    int oi = __shfl_xor(besti, off, 64);
    if (ov < bestd || (ov == bestd && oi < besti)) {
      bestd = ov;
      besti = oi;
    }
  }
  if (q8 == 0) out[row] = besti;
}

// ================= fallback (round-1 verbatim, passed at 1654us) =================
__global__ __launch_bounds__(256) void k_merge(const float* __restrict__ candv,
                                               const int* __restrict__ candi,
                                               int* __restrict__ out) {
  int n = blockIdx.x * 256 + threadIdx.x;
  float v0 = candv[n], v1 = candv[NROW + n];
  int i0 = candi[n], i1 = candi[NROW + n];
  out[n] = (v1 < v0) ? i1 : i0;
}

template <int SPLIT>
__global__ __launch_bounds__(256, 2) void k_main_fb(const float* __restrict__ z,
                                                    const float* __restrict__ e,
                                                    const float* __restrict__ es,
                                                    float* __restrict__ candv,
                                                    int* __restrict__ candi,
                                                    int* __restrict__ outd) {
  extern __shared__ char smemc[];
  float* As = (float*)smemc;
  float* Bs = (float*)(smemc + 16384);
  double* zred = (double*)(smemc + 16384 + 32768);
  float* zsf = (float*)(smemc + 16384 + 32768 + 2048);
  const int tid = threadIdx.x;
  const int lane = tid & 63;
  const int wv = tid >> 6;
  const int tm = tid & 7;
  const int tn = tid >> 3;
  const int rt = (int)blockIdx.x / SPLIT;
  const int sp = (int)blockIdx.x % SPLIT;
  const int bb = rt >> 4;
  const int hw0 = (rt & 15) << 6;
  const float* zb = z + bb * (EDIM * 1024) + hw0;
  const int codeBase = sp * (NCODE / SPLIT);
  const int NSTEP = (NCODE / SPLIT) / 256 * 8;
  auto stageA = [&](int buf, int gts) {
    const int k0 = (gts & 7) * 32;
    const float* g0 = zb + (size_t)k0 * 1024 + lane;
    float* l0 = As + buf * 2048 + (wv * 8) * 64;
#pragma unroll
    for (int s = 0; s < 8; ++s) gll4(g0 + (size_t)(wv * 8 + s) * 1024, l0 + s * 64);
  };
  float4 bpre[8];
  auto loadB = [&](int gts) {
    const int ct = gts >> 3, k0 = (gts & 7) * 32;
    const float* g = e + (size_t)(codeBase + ct * 256 + tid) * 256 + k0;
#pragma unroll
    for (int s = 0; s < 8; ++s) bpre[s] = *(const float4*)(g + s * 4);
  };
  auto writeB = [&](int buf) {
    float* bw_ = Bs + buf * 8192 + tid;
#pragma unroll
    for (int s = 0; s < 8; ++s) {
      bw_[(4 * s + 0) * 256] = bpre[s].x;
      bw_[(4 * s + 1) * 256] = bpre[s].y;
      bw_[(4 * s + 2) * 256] = bpre[s].z;
      bw_[(4 * s + 3) * 256] = bpre[s].w;
    }
  };
  stageA(0, 0);
  loadB(0);
  {
    const int m = tid & 63, qt = tid >> 6;
    const float* zp = zb + (size_t)(qt * 64) * 1024 + m;
    double s = 0.0;
    for (int k = 0; k < 64; ++k) {
      float v = zp[(size_t)k * 1024];
      s = fma((double)v, (double)v, s);
    }
    zred[qt * 64 + m] = s;
  }
  writeB(0);
  __syncthreads();
  if (tid < 64) {
    double sz = (zred[tid] + zred[64 + tid]) + (zred[128 + tid] + zred[192 + tid]);
    zsf[tid] = (float)sz;
  }
  __syncthreads();
  float zsr[8];
#pragma unroll
  for (int i = 0; i < 8; ++i) zsr[i] = zsf[tm * 8 + i];
  __syncthreads();
  float bestv[8];
  int besti[8];
#pragma unroll
  for (int i = 0; i < 8; ++i) {
    bestv[i] = 3.402823466e+38f;
    besti[i] = 0;
  }
  float acc[8][8];
  int cur = 0;
#pragma unroll 1
  for (int step = 0; step < NSTEP; ++step) {
    const int kc = step & 7, ct = step >> 3;
    if (step + 1 < NSTEP) {
      stageA(cur ^ 1, step + 1);
      loadB(step + 1);
    }
    if (kc == 0) {
#pragma unroll
      for (int i = 0; i < 8; ++i)
#pragma unroll
        for (int j = 0; j < 8; ++j) acc[i][j] = 0.0f;
    }
    const float* ak = As + cur * 2048 + tm * 8;
    const float* bk = Bs + cur * 8192 + tn * 8;
#pragma unroll 4
    for (int k = 0; k < 32; ++k) {
      float4 a0 = *(const float4*)(ak + k * 64);
      float4 a1 = *(const float4*)(ak + k * 64 + 4);
      float4 b0 = *(const float4*)(bk + k * 256);
      float4 b1 = *(const float4*)(bk + k * 256 + 4);
      float av[8] = {a0.x, a0.y, a0.z, a0.w, a1.x, a1.y, a1.z, a1.w};
      float bw[8] = {b0.x, b0.y, b0.z, b0.w, b1.x, b1.y, b1.z, b1.w};
#pragma unroll
      for (int i = 0; i < 8; ++i)
#pragma unroll
        for (int j = 0; j < 8; ++j) acc[i][j] = fmaf(av[i], bw[j], acc[i][j]);
    }
    if (step + 1 < NSTEP) writeB(cur ^ 1);
    if (kc == 7) {
      const int cb = codeBase + ct * 256 + tn * 8;
#pragma unroll
      for (int j = 0; j < 8; ++j) {
        float ej = es[cb + j];
#pragma unroll
        for (int i = 0; i < 8; ++i) {
          float d = (zsr[i] + ej) - 2.0f * acc[i][j];
          if (d < bestv[i]) {
            bestv[i] = d;
            besti[i] = cb + j;
          }
        }
      }
    }
    __syncthreads();
    cur ^= 1;
  }
  float* Lv = (float*)(smemc + 16384);
  int* Li = (int*)(smemc + 16384 + 8192);
#pragma unroll
  for (int i = 0; i < 8; ++i) {
    Lv[(tm * 8 + i) * 32 + tn] = bestv[i];
    Li[(tm * 8 + i) * 32 + tn] = besti[i];
  }
  __syncthreads();
  if (tid < 64) {
    float bv = Lv[tid * 32];
    int bi = Li[tid * 32];
#pragma unroll 1
    for (int g2 = 1; g2 < 32; ++g2) {
      float v = Lv[tid * 32 + g2];
      int ii = Li[tid * 32 + g2];
      if (v < bv || (v == bv && ii < bi)) {
        bv = v;
        bi = ii;
      }
    }
    if (SPLIT == 1) outd[rt * 64 + tid] = bi;
    else {
      candv[sp * NROW + rt * 64 + tid] = bv;
      candi[sp * NROW + rt * 64 + tid] = bi;
    }
  }
}

extern "C" void kernel_launch(void* const* d_in, const int* in_sizes, int n_in,
                              void* d_out, int out_size, void* d_ws, size_t ws_size,
                              hipStream_t stream) {
  const float* z = (const float*)d_in[0];
  const float* e = (const float*)d_in[1];
  int* out = (int*)d_out;

  char* ws = (char*)d_ws;
  float* es = (float*)ws;
  const size_t off_zh = 65536;
  const size_t off_eh = off_zh + (size_t)NROW * EDIM * 2;
  const size_t off_lmin = off_eh + (size_t)NCODE * EDIM * 2;
  const size_t off_masks = off_lmin + (size_t)NROW * NBN * 4;
  const size_t need = off_masks + (size_t)NROW * NBN * 16;

  if (ws_size >= need) {
    _Float16* Zh = (_Float16*)(ws + off_zh);
    _Float16* Eh = (_Float16*)(ws + off_eh);
    float* lmin = (float*)(ws + off_lmin);
    uint4* masks = (uint4*)(ws + off_masks);
    k_prep_e<<<dim3(NCODE / 4), dim3(256), 0, stream>>>(e, es, Eh);
    k_cvt_z<<<dim3(512), dim3(256), 0, stream>>>(z, Zh);
    k_gemm<<<dim3(16384), dim3(256), 0, stream>>>(Zh, Eh, lmin, masks);
    const int rs_smem = (EDIM * 33 + NBN * 33) * 4;  // 50688
    hipFuncSetAttribute(reinterpret_cast<const void*>(&k_rescore),
                        hipFuncAttributeMaxDynamicSharedMemorySize, rs_smem);
    k_rescore<<<dim3(512), dim3(256), rs_smem, stream>>>(z, e, es, lmin, masks, out);
  } else {
    k_es<<<dim3(NCODE / 4), dim3(256), 0, stream>>>(e, es);
    float* candv = (float*)(ws + 65536);
    int* candi = (int*)(ws + 65536 + 131072);
    const size_t smem = 16384 + 65536;
    if (ws_size >= 65536 + 131072 + 131072) {
      hipFuncSetAttribute(reinterpret_cast<const void*>(&k_main_fb<2>),
                          hipFuncAttributeMaxDynamicSharedMemorySize, (int)smem);
      k_main_fb<2><<<dim3(512), dim3(256), smem, stream>>>(z, e, es, candv, candi, out);
      k_merge<<<dim3(NROW / 256), dim3(256), 0, stream>>>(candv, candi, out);
    } else {
      hipFuncSetAttribute(reinterpret_cast<const void*>(&k_main_fb<1>),
                          hipFuncAttributeMaxDynamicSharedMemorySize, (int)smem);
      k_main_fb<1><<<dim3(256), dim3(256), smem, stream>>>(z, e, es, candv, candi, out);
    }
  }
}